// Round 6
// baseline (15.434 us; speedup 1.0000x reference)
//
#include <hip/hip_runtime.h>
#include <math.h>

// Reranker tie-aware RankNet loss — R6.
// B=4096 rows, n=64. TWO waves per row (each handles a 32-wide b-slice);
// 1024 blocks x 512 threads = 8192 waves -> 8 waves/SIMD (max occupancy).
//   - group-end e via one __ballot + ctz;  mask (b > e);  cnt analytic
//   - softplus in base-2, LOG-OF-PRODUCT: per pair only ONE trans op
//       sp/ln2 = max(t,0) + log2(1 + 2^-|t|)
//       sum log2 terms == log2( prod (1 + masked 2^-|t|) )  [<=32 factors <= 2^32]
//   - per-pair: readlane, sub, exp2, cmp, cndmask, fmac(prod), max, cndmask, add
//   - 8 independent chains (8 prods, 8 relu-sums); one v_log_f32 per lane at end
// Two-stage deterministic reduction: per-block partials -> finalize kernel.

#define N 64
#define WPB 8                   // waves per 512-thread block (4 rows x 2 halves)
#define LN2 0.6931471805599453f
#define LOG2E 1.4426950408889634f

__device__ __forceinline__ float readlane_f(float v, int srclane) {
    return __int_as_float(__builtin_amdgcn_readlane(__float_as_int(v), srclane));
}

#define TERM(i, p, r) do {                                         \
    const int b_ = lo + bb + (i);                                  \
    float t_  = readlane_f(pa2, b_) - pa2;                         \
    float g_  = __builtin_amdgcn_exp2f(-fabsf(t_));                \
    bool  m_  = b_ > e;                                            \
    float gm_ = m_ ? g_ : 0.0f;                                    \
    p = fmaf(gm_, p, p);              /* p *= (1 + masked g) */    \
    r += m_ ? fmaxf(t_, 0.0f) : 0.0f;                              \
} while (0)

__global__ __launch_bounds__(512, 8) void rank_loss_partial(
    const float* __restrict__ logits, const int* __restrict__ kd,
    float2* __restrict__ partials, int B)
{
    const int lane = threadIdx.x & 63;
    const int wave = threadIdx.x >> 6;           // 0..7
    const int row  = blockIdx.x * 4 + (wave >> 1);
    const int lo   = (wave & 1) << 5;            // b-slice start: 0 or 32

    float p0=1.f,p1=1.f,p2=1.f,p3=1.f,p4=1.f,p5=1.f,p6=1.f,p7=1.f;
    float r0=0.f,r1=0.f,r2=0.f,r3=0.f,r4=0.f,r5=0.f,r6=0.f,r7=0.f;
    float cnt = 0.f;
    float psum = 0.f;

    if (row < B) {
        const int base = row * N + lane;
        const int   k   = kd[base];
        const float pa2 = logits[base] * LOG2E;

        // group-end lane e: smallest j >= lane with (j==63 or k[j]!=k[j+1])
        const int knext = __shfl_down(k, 1);
        unsigned long long endm = __ballot(lane == 63 || k != knext);
        const int e = lane + __builtin_ctzll(endm >> lane);   // bit 63 set
        const int lowB = max(e + 1, lo);
        cnt = (float)max(0, lo + 32 - lowB);     // masked pairs in this slice

        #pragma unroll 1
        for (int bb = 0; bb < 32; bb += 8) {
            TERM(0, p0, r0); TERM(1, p1, r1); TERM(2, p2, r2); TERM(3, p3, r3);
            TERM(4, p4, r4); TERM(5, p5, r5); TERM(6, p6, r6); TERM(7, p7, r7);
        }

        float prod = ((p0 * p1) * (p2 * p3)) * ((p4 * p5) * (p6 * p7));
        float rsum = ((r0 + r1) + (r2 + r3)) + ((r4 + r5) + (r6 + r7));
        psum = rsum + __builtin_amdgcn_logf(prod);   // v_log_f32 == log2
    }

    #pragma unroll
    for (int off = 32; off; off >>= 1) {
        psum += __shfl_down(psum, off);
        cnt  += __shfl_down(cnt,  off);
    }

    __shared__ float ssum[WPB], scnt[WPB];
    if (lane == 0) { ssum[wave] = psum; scnt[wave] = cnt; }
    __syncthreads();
    if (threadIdx.x == 0) {
        float s = 0.f, c = 0.f;
        #pragma unroll
        for (int w = 0; w < WPB; ++w) { s += ssum[w]; c += scnt[w]; }
        partials[blockIdx.x] = make_float2(s, c);
    }
}

__global__ __launch_bounds__(256) void rank_loss_final(
    const float2* __restrict__ partials, float* __restrict__ out, int nPartials)
{
    const int t = threadIdx.x;
    float s = 0.f, c = 0.f;
    for (int i = t; i < nPartials; i += 256) {
        float2 p = partials[i];
        s += p.x; c += p.y;
    }
    #pragma unroll
    for (int off = 32; off; off >>= 1) {
        s += __shfl_down(s, off);
        c += __shfl_down(c, off);
    }
    __shared__ float ss[4], sc[4];
    const int lane = t & 63, wavei = t >> 6;
    if (lane == 0) { ss[wavei] = s; sc[wavei] = c; }
    __syncthreads();
    if (t == 0) {
        float S = 0.f, C = 0.f;
        #pragma unroll
        for (int w = 0; w < 4; ++w) { S += ss[w]; C += sc[w]; }
        out[0] = S * LN2 / C;
    }
}

extern "C" void kernel_launch(void* const* d_in, const int* in_sizes, int n_in,
                              void* d_out, int out_size, void* d_ws, size_t ws_size,
                              hipStream_t stream) {
    const float* logits = (const float*)d_in[0];
    const int*   kd     = (const int*)d_in[1];
    float*       out    = (float*)d_out;
    const int B = in_sizes[1] / N;              // 4096
    const int nBlocks = B / 4;                  // 1024 (4 rows per block)
    float2* partials = (float2*)d_ws;           // 8 KiB of ws

    rank_loss_partial<<<nBlocks, 512, 0, stream>>>(logits, kd, partials, B);
    rank_loss_final<<<1, 256, 0, stream>>>(partials, out, nBlocks);
}